// Round 1
// baseline (1605.772 us; speedup 1.0000x reference)
//
#include <hip/hip_runtime.h>

#define IN_FEAT 256
#define OUT_FEAT 64

constexpr int ROWS_PER_BLOCK = 64;

// P_self -> acc (initializes it), P_neigh -> Pn.
// Block: 256 threads (4 waves). Each wave: 16 rows x 64 cols, lane = col.
// W_self/W_neigh staged in LDS in two 128-deep K halves (64 KB total).
__global__ __launch_bounds__(256) void gemm_dual(
    const float* __restrict__ feat,
    const float* __restrict__ Wself,
    const float* __restrict__ Wneigh,
    float* __restrict__ acc,   // [N,64] <- feat@Wself
    float* __restrict__ Pn,    // [N,64] <- feat@Wneigh
    int n_nodes)
{
    __shared__ float sWs[128][64];
    __shared__ float sWn[128][64];
    const int t    = threadIdx.x;
    const int wave = t >> 6;
    const int lane = t & 63;
    const int base = blockIdx.x * ROWS_PER_BLOCK;

    float aS[16], aN[16];
#pragma unroll
    for (int i = 0; i < 16; ++i) { aS[i] = 0.f; aN[i] = 0.f; }

    for (int half = 0; half < 2; ++half) {
        if (half) __syncthreads();
        const float4* ws4 = (const float4*)(Wself + half * 128 * OUT_FEAT);
        const float4* wn4 = (const float4*)(Wneigh + half * 128 * OUT_FEAT);
        float4* ds = (float4*)&sWs[0][0];
        float4* dn = (float4*)&sWn[0][0];
        for (int i = t; i < 128 * OUT_FEAT / 4; i += 256) { ds[i] = ws4[i]; dn[i] = wn4[i]; }
        __syncthreads();

#pragma unroll
        for (int g = 0; g < 4; ++g) {
            const int r0 = base + g * 16 + wave * 4;
            const float* f0 = feat + (size_t)min(r0 + 0, n_nodes - 1) * IN_FEAT + half * 128;
            const float* f1 = feat + (size_t)min(r0 + 1, n_nodes - 1) * IN_FEAT + half * 128;
            const float* f2 = feat + (size_t)min(r0 + 2, n_nodes - 1) * IN_FEAT + half * 128;
            const float* f3 = feat + (size_t)min(r0 + 3, n_nodes - 1) * IN_FEAT + half * 128;
#pragma unroll 4
            for (int k = 0; k < 128; ++k) {
                const float w0 = sWs[k][lane];   // 2 lanes/bank: free
                const float w1 = sWn[k][lane];
                float f;
                f = f0[k]; aS[g*4+0] += f*w0; aN[g*4+0] += f*w1;
                f = f1[k]; aS[g*4+1] += f*w0; aN[g*4+1] += f*w1;
                f = f2[k]; aS[g*4+2] += f*w0; aN[g*4+2] += f*w1;
                f = f3[k]; aS[g*4+3] += f*w0; aN[g*4+3] += f*w1;
            }
        }
    }

#pragma unroll
    for (int g = 0; g < 4; ++g) {
#pragma unroll
        for (int j = 0; j < 4; ++j) {
            const int r = base + g * 16 + wave * 4 + j;
            if (r < n_nodes) {
                acc[(size_t)r * OUT_FEAT + lane] = aS[g*4+j];
                Pn [(size_t)r * OUT_FEAT + lane] = aN[g*4+j];
            }
        }
    }
}

// acc[dst] += w * P_neigh[src]; 16 threads per edge, float4 gather + 4 atomics.
__global__ __launch_bounds__(256) void scatter_edges(
    const float* __restrict__ Pn,
    const int* __restrict__ esrc,
    const int* __restrict__ edst,
    const float* __restrict__ ew,
    float* __restrict__ acc,
    int n_edges)
{
    const long long tid = (long long)blockIdx.x * blockDim.x + threadIdx.x;
    const int e = (int)(tid >> 4);
    if (e >= n_edges) return;
    const int c = ((int)tid & 15) << 2;

    const int   s = esrc[e];
    const int   d = edst[e];
    const float w = ew[e];

    const float4 v = *(const float4*)(Pn + (size_t)s * OUT_FEAT + c);
    float* a = acc + (size_t)d * OUT_FEAT + c;
    atomicAdd(a + 0, w * v.x);
    atomicAdd(a + 1, w * v.y);
    atomicAdd(a + 2, w * v.z);
    atomicAdd(a + 3, w * v.w);
}

__global__ __launch_bounds__(256) void relu_out(
    const float4* __restrict__ acc, float4* __restrict__ out, int n4)
{
    const int i = blockIdx.x * blockDim.x + threadIdx.x;
    if (i < n4) {
        float4 v = acc[i];
        v.x = fmaxf(v.x, 0.f);
        v.y = fmaxf(v.y, 0.f);
        v.z = fmaxf(v.z, 0.f);
        v.w = fmaxf(v.w, 0.f);
        out[i] = v;
    }
}

extern "C" void kernel_launch(void* const* d_in, const int* in_sizes, int n_in,
                              void* d_out, int out_size, void* d_ws, size_t ws_size,
                              hipStream_t stream) {
    const float* feat   = (const float*)d_in[0];
    const int*   esrc   = (const int*)  d_in[1];
    const int*   edst   = (const int*)  d_in[2];
    const float* ew     = (const float*)d_in[3];
    const float* Wself  = (const float*)d_in[4];
    const float* Wneigh = (const float*)d_in[5];

    const int n_nodes = in_sizes[0] / IN_FEAT;
    const int n_edges = in_sizes[1];

    float* acc = (float*)d_ws;                          // [N,64] self-term then += neigh
    float* Pn  = acc + (size_t)n_nodes * OUT_FEAT;      // [N,64] feat @ W_neigh
    float* out = (float*)d_out;

    const int gemm_blocks = (n_nodes + ROWS_PER_BLOCK - 1) / ROWS_PER_BLOCK;
    gemm_dual<<<gemm_blocks, 256, 0, stream>>>(feat, Wself, Wneigh, acc, Pn, n_nodes);

    const long long sthreads = (long long)n_edges * 16;
    const int sblocks = (int)((sthreads + 255) / 256);
    scatter_edges<<<sblocks, 256, 0, stream>>>(Pn, esrc, edst, ew, acc, n_edges);

    const int n4 = n_nodes * OUT_FEAT / 4;
    relu_out<<<(n4 + 255) / 256, 256, 0, stream>>>((const float4*)acc, (float4*)out, n4);
}

// Round 2
// 541.768 us; speedup vs baseline: 2.9639x; 2.9639x over previous
//
#include <hip/hip_runtime.h>

#define IN_FEAT 256
#define OUT_FEAT 64

constexpr int ROWS_PER_BLOCK = 64;

// ---------------- GEMM: acc = feat@Wself, Pn = feat@Wneigh ----------------
__global__ __launch_bounds__(256) void gemm_dual(
    const float* __restrict__ feat,
    const float* __restrict__ Wself,
    const float* __restrict__ Wneigh,
    float* __restrict__ acc,   // [N,64] <- feat@Wself
    float* __restrict__ Pn,    // [N,64] <- feat@Wneigh
    int n_nodes)
{
    __shared__ float sWs[128][64];
    __shared__ float sWn[128][64];
    const int t    = threadIdx.x;
    const int wave = t >> 6;
    const int lane = t & 63;
    const int base = blockIdx.x * ROWS_PER_BLOCK;

    float aS[16], aN[16];
#pragma unroll
    for (int i = 0; i < 16; ++i) { aS[i] = 0.f; aN[i] = 0.f; }

    for (int half = 0; half < 2; ++half) {
        if (half) __syncthreads();
        const float4* ws4 = (const float4*)(Wself + half * 128 * OUT_FEAT);
        const float4* wn4 = (const float4*)(Wneigh + half * 128 * OUT_FEAT);
        float4* ds = (float4*)&sWs[0][0];
        float4* dn = (float4*)&sWn[0][0];
        for (int i = t; i < 128 * OUT_FEAT / 4; i += 256) { ds[i] = ws4[i]; dn[i] = wn4[i]; }
        __syncthreads();

#pragma unroll
        for (int g = 0; g < 4; ++g) {
            const int r0 = base + g * 16 + wave * 4;
            const float* f0 = feat + (size_t)min(r0 + 0, n_nodes - 1) * IN_FEAT + half * 128;
            const float* f1 = feat + (size_t)min(r0 + 1, n_nodes - 1) * IN_FEAT + half * 128;
            const float* f2 = feat + (size_t)min(r0 + 2, n_nodes - 1) * IN_FEAT + half * 128;
            const float* f3 = feat + (size_t)min(r0 + 3, n_nodes - 1) * IN_FEAT + half * 128;
#pragma unroll 4
            for (int k = 0; k < 128; ++k) {
                const float w0 = sWs[k][lane];
                const float w1 = sWn[k][lane];
                float f;
                f = f0[k]; aS[g*4+0] += f*w0; aN[g*4+0] += f*w1;
                f = f1[k]; aS[g*4+1] += f*w0; aN[g*4+1] += f*w1;
                f = f2[k]; aS[g*4+2] += f*w0; aN[g*4+2] += f*w1;
                f = f3[k]; aS[g*4+3] += f*w0; aN[g*4+3] += f*w1;
            }
        }
    }

#pragma unroll
    for (int g = 0; g < 4; ++g) {
#pragma unroll
        for (int j = 0; j < 4; ++j) {
            const int r = base + g * 16 + wave * 4 + j;
            if (r < n_nodes) {
                acc[(size_t)r * OUT_FEAT + lane] = aS[g*4+j];
                Pn [(size_t)r * OUT_FEAT + lane] = aN[g*4+j];
            }
        }
    }
}

// ---------------- CSR build: histogram -> scan -> bucket scatter ----------
__global__ __launch_bounds__(256) void hist(
    const int* __restrict__ edst, int* __restrict__ cnt, int n_edges)
{
    const int e = blockIdx.x * 256 + threadIdx.x;
    if (e < n_edges) atomicAdd(&cnt[edst[e]], 1);
}

// Single-block exclusive scan over n counts -> rowptr[0..n], cursor copy.
__global__ __launch_bounds__(1024) void scan_rowptr(
    const int* __restrict__ cnt,
    int* __restrict__ rowptr,
    int* __restrict__ cursor, int n)
{
    __shared__ int wsum[17];
    __shared__ int carry;
    if (threadIdx.x == 0) carry = 0;
    __syncthreads();
    const int lane = threadIdx.x & 63;
    const int wave = threadIdx.x >> 6;
    for (int base = 0; base < n; base += 1024) {
        const int i = base + (int)threadIdx.x;
        const int v = (i < n) ? cnt[i] : 0;
        int s = v;                       // inclusive wave scan
#pragma unroll
        for (int off = 1; off < 64; off <<= 1) {
            int tt = __shfl_up(s, off, 64);
            if (lane >= off) s += tt;
        }
        if (lane == 63) wsum[wave] = s;
        __syncthreads();
        if (threadIdx.x == 0) {          // serial scan of 16 wave sums
            int run = 0;
#pragma unroll
            for (int k = 0; k < 16; ++k) { int tt = wsum[k]; wsum[k] = run; run += tt; }
            wsum[16] = run;
        }
        __syncthreads();
        if (i < n) {
            const int excl = carry + wsum[wave] + (s - v);
            rowptr[i] = excl;
            cursor[i] = excl;
        }
        __syncthreads();                 // everyone has read carry
        if (threadIdx.x == 0) carry += wsum[16];
        __syncthreads();
    }
    if (threadIdx.x == 0) rowptr[n] = carry;
}

// Place (src, weight) into dst-sorted buckets.
__global__ __launch_bounds__(256) void sort_edges(
    const int* __restrict__ esrc,
    const int* __restrict__ edst,
    const float* __restrict__ ew,
    int* __restrict__ cursor,
    int2* __restrict__ epk, int n_edges)
{
    const int e = blockIdx.x * 256 + threadIdx.x;
    if (e >= n_edges) return;
    const int d = edst[e];
    const int pos = atomicAdd(&cursor[d], 1);
    epk[pos] = make_int2(esrc[e], __float_as_int(ew[e]));
}

// ---------------- Gather: one wave per dst node, fused self+ReLU ----------
__global__ __launch_bounds__(256) void gather(
    const int2* __restrict__ epk,
    const int* __restrict__ rowptr,
    const float* __restrict__ Pn,
    const float* __restrict__ acc,
    float* __restrict__ out, int n_nodes)
{
    const int node = blockIdx.x * 4 + (threadIdx.x >> 6);
    if (node >= n_nodes) return;
    const int lane = threadIdx.x & 63;
    const int esub = lane >> 4;          // 0..3: 4 edges in flight per wave
    const int c    = (lane & 15) << 2;   // feature quad 0..60

    const int beg = rowptr[node];
    const int end = rowptr[node + 1];

    float4 a = make_float4(0.f, 0.f, 0.f, 0.f);
    for (int e = beg + esub; e < end; e += 4) {
        const int2 p = epk[e];
        const float w = __int_as_float(p.y);
        const float4 v = *(const float4*)(Pn + (size_t)p.x * OUT_FEAT + c);
        a.x += w * v.x;
        a.y += w * v.y;
        a.z += w * v.z;
        a.w += w * v.w;
    }
    // reduce the 4 esub groups (lanes differing in bits 4,5)
#pragma unroll
    for (int m = 16; m < 64; m <<= 1) {
        a.x += __shfl_xor(a.x, m, 64);
        a.y += __shfl_xor(a.y, m, 64);
        a.z += __shfl_xor(a.z, m, 64);
        a.w += __shfl_xor(a.w, m, 64);
    }
    if (esub == 0) {
        const float4 s = *(const float4*)(acc + (size_t)node * OUT_FEAT + c);
        float4 o;
        o.x = fmaxf(s.x + a.x, 0.f);
        o.y = fmaxf(s.y + a.y, 0.f);
        o.z = fmaxf(s.z + a.z, 0.f);
        o.w = fmaxf(s.w + a.w, 0.f);
        *(float4*)(out + (size_t)node * OUT_FEAT + c) = o;
    }
}

extern "C" void kernel_launch(void* const* d_in, const int* in_sizes, int n_in,
                              void* d_out, int out_size, void* d_ws, size_t ws_size,
                              hipStream_t stream) {
    const float* feat   = (const float*)d_in[0];
    const int*   esrc   = (const int*)  d_in[1];
    const int*   edst   = (const int*)  d_in[2];
    const float* ew     = (const float*)d_in[3];
    const float* Wself  = (const float*)d_in[4];
    const float* Wneigh = (const float*)d_in[5];

    const int n_nodes = in_sizes[0] / IN_FEAT;
    const int n_edges = in_sizes[1];

    // workspace layout (8B-aligned segments)
    float* acc    = (float*)d_ws;                         // N*64 f32
    float* Pn     = acc + (size_t)n_nodes * OUT_FEAT;     // N*64 f32
    int2*  epk    = (int2*)(Pn + (size_t)n_nodes * OUT_FEAT); // E int2
    int*   cnt    = (int*)(epk + n_edges);                // N
    int*   rowptr = cnt + n_nodes;                        // N+1
    int*   cursor = rowptr + n_nodes + 1;                 // N
    float* out    = (float*)d_out;

    hipMemsetAsync(cnt, 0, (size_t)n_nodes * sizeof(int), stream);

    const int gemm_blocks = (n_nodes + ROWS_PER_BLOCK - 1) / ROWS_PER_BLOCK;
    gemm_dual<<<gemm_blocks, 256, 0, stream>>>(feat, Wself, Wneigh, acc, Pn, n_nodes);

    hist<<<(n_edges + 255) / 256, 256, 0, stream>>>(edst, cnt, n_edges);
    scan_rowptr<<<1, 1024, 0, stream>>>(cnt, rowptr, cursor, n_nodes);
    sort_edges<<<(n_edges + 255) / 256, 256, 0, stream>>>(esrc, edst, ew, cursor, epk, n_edges);

    gather<<<(n_nodes + 3) / 4, 256, 0, stream>>>(epk, rowptr, Pn, acc, out, n_nodes);
}

// Round 3
// 374.331 us; speedup vs baseline: 4.2897x; 1.4473x over previous
//
#include <hip/hip_runtime.h>

#define IN_FEAT 256
#define OUT_FEAT 64

typedef __attribute__((ext_vector_type(8))) short bf16x8;
typedef __attribute__((ext_vector_type(4))) float f32x4;

static __device__ __forceinline__ short f2bf(float f) {
    unsigned u = __float_as_uint(f);
    unsigned r = (u + 0x7FFFu + ((u >> 16) & 1u)) >> 16;
    return (short)r;
}

// ---------------- Wfrag: pre-swizzle [Wself|Wneigh] into MFMA B-fragment order
// Entry (kstep, ntile, lane) -> 8 bf16: B[k=kstep*32+quad*8+j][n=ntile*16+(lane&15)]
// Wfrag flat index: (kstep*8 + ntile)*64 + lane.  64 KB total.
__global__ __launch_bounds__(256) void wfrag_build(
    const float* __restrict__ Wself,
    const float* __restrict__ Wneigh,
    bf16x8* __restrict__ Wfrag)
{
    const int t = blockIdx.x * 256 + threadIdx.x;   // 0..4095
    const int kstep = t >> 9;
    const int ntile = (t >> 6) & 7;
    const int lane  = t & 63;
    const int quad  = lane >> 4;
    const int n     = ntile * 16 + (lane & 15);
    const float* src = (n < OUT_FEAT) ? (Wself + n) : (Wneigh + (n - OUT_FEAT));
    const int k0 = kstep * 32 + quad * 8;
    bf16x8 v;
#pragma unroll
    for (int j = 0; j < 8; ++j) v[j] = f2bf(src[(size_t)(k0 + j) * OUT_FEAT]);
    Wfrag[t] = v;
}

// ---------------- MFMA GEMM: acc = feat@Wself, Pn = feat@Wneigh --------------
// 4 waves/block; wave w computes rows [base+16w, base+16w+16) x 128 cols.
// No LDS: A loaded as fp32 dwordx4 pairs + cvt; B-frags from Wfrag (L2-hot).
__global__ __launch_bounds__(256) void gemm_mfma(
    const float* __restrict__ feat,
    const bf16x8* __restrict__ Wfrag,
    float* __restrict__ acc,   // [N,64] feat@Wself
    float* __restrict__ Pn,    // [N,64] feat@Wneigh
    int n_nodes)
{
    const int wave = threadIdx.x >> 6;
    const int lane = threadIdx.x & 63;
    const int quad = lane >> 4;
    const int l15  = lane & 15;
    const int row0 = blockIdx.x * 64 + wave * 16;

    f32x4 c[8];
#pragma unroll
    for (int i = 0; i < 8; ++i) c[i] = (f32x4){0.f, 0.f, 0.f, 0.f};

    const int arow = min(row0 + l15, n_nodes - 1);
    const float* afeat = feat + (size_t)arow * IN_FEAT + quad * 8;

#pragma unroll
    for (int kstep = 0; kstep < 8; ++kstep) {
        const float4 x = *(const float4*)(afeat + kstep * 32);
        const float4 y = *(const float4*)(afeat + kstep * 32 + 4);
        bf16x8 a;
        a[0] = f2bf(x.x); a[1] = f2bf(x.y); a[2] = f2bf(x.z); a[3] = f2bf(x.w);
        a[4] = f2bf(y.x); a[5] = f2bf(y.y); a[6] = f2bf(y.z); a[7] = f2bf(y.w);
        bf16x8 b[8];
#pragma unroll
        for (int nt = 0; nt < 8; ++nt) b[nt] = Wfrag[(kstep * 8 + nt) * 64 + lane];
#pragma unroll
        for (int nt = 0; nt < 8; ++nt)
            c[nt] = __builtin_amdgcn_mfma_f32_16x16x32_bf16(a, b[nt], c[nt], 0, 0, 0);
    }

    // C layout: col = ntile*16 + (lane&15), row = row0 + quad*4 + reg
#pragma unroll
    for (int nt = 0; nt < 8; ++nt) {
        float* dst = (nt < 4) ? acc : Pn;
        const int col = (nt & 3) * 16 + l15;
#pragma unroll
        for (int r = 0; r < 4; ++r) {
            const int row = row0 + quad * 4 + r;
            if (row < n_nodes) dst[(size_t)row * OUT_FEAT + col] = c[nt][r];
        }
    }
}

// ---------------- CSR build ----------------
__global__ __launch_bounds__(256) void hist(
    const int* __restrict__ edst, int* __restrict__ cnt, int n_edges)
{
    const int e = blockIdx.x * 256 + threadIdx.x;
    if (e < n_edges) atomicAdd(&cnt[edst[e]], 1);
}

// phase 1: per-1024-chunk sums
__global__ __launch_bounds__(1024) void scan_p1(
    const int* __restrict__ cnt, int* __restrict__ bsum, int n)
{
    __shared__ int wsum[16];
    const int i = blockIdx.x * 1024 + threadIdx.x;
    int v = (i < n) ? cnt[i] : 0;
#pragma unroll
    for (int m = 32; m >= 1; m >>= 1) v += __shfl_xor(v, m, 64);
    if ((threadIdx.x & 63) == 0) wsum[threadIdx.x >> 6] = v;
    __syncthreads();
    if (threadIdx.x == 0) {
        int s = 0;
#pragma unroll
        for (int k = 0; k < 16; ++k) s += wsum[k];
        bsum[blockIdx.x] = s;
    }
}

// phase 2: exclusive scan of <=64 chunk sums (single wave); writes rowptr[n]=total
__global__ __launch_bounds__(64) void scan_p2(
    const int* __restrict__ bsum, int* __restrict__ boff,
    int* __restrict__ rowptr, int nb, int n)
{
    const int t = threadIdx.x;
    const int v = (t < nb) ? bsum[t] : 0;
    int s = v;
#pragma unroll
    for (int off = 1; off < 64; off <<= 1) {
        int tt = __shfl_up(s, off, 64);
        if (t >= off) s += tt;
    }
    if (t < nb) boff[t] = s - v;
    if (t == nb - 1) rowptr[n] = s;
}

// phase 3: local scan + chunk offset -> rowptr, cursor
__global__ __launch_bounds__(1024) void scan_p3(
    const int* __restrict__ cnt, const int* __restrict__ boff,
    int* __restrict__ rowptr, int* __restrict__ cursor, int n)
{
    __shared__ int wpre[16];
    const int lane = threadIdx.x & 63;
    const int wave = threadIdx.x >> 6;
    const int i = blockIdx.x * 1024 + threadIdx.x;
    const int v = (i < n) ? cnt[i] : 0;
    int s = v;
#pragma unroll
    for (int off = 1; off < 64; off <<= 1) {
        int tt = __shfl_up(s, off, 64);
        if (lane >= off) s += tt;
    }
    if (lane == 63) wpre[wave] = s;
    __syncthreads();
    if (threadIdx.x == 0) {
        int run = 0;
#pragma unroll
        for (int k = 0; k < 16; ++k) { int tt = wpre[k]; wpre[k] = run; run += tt; }
    }
    __syncthreads();
    if (i < n) {
        const int excl = boff[blockIdx.x] + wpre[wave] + (s - v);
        rowptr[i] = excl;
        cursor[i] = excl;
    }
}

__global__ __launch_bounds__(256) void sort_edges(
    const int* __restrict__ esrc,
    const int* __restrict__ edst,
    const float* __restrict__ ew,
    int* __restrict__ cursor,
    int2* __restrict__ epk, int n_edges)
{
    const int e = blockIdx.x * 256 + threadIdx.x;
    if (e >= n_edges) return;
    const int d = edst[e];
    const int pos = atomicAdd(&cursor[d], 1);
    epk[pos] = make_int2(esrc[e], __float_as_int(ew[e]));
}

// ---------------- Gather: node per wave, feature per lane, fused self+ReLU ---
__global__ __launch_bounds__(256) void gather(
    const int2* __restrict__ epk,
    const int* __restrict__ rowptr,
    const float* __restrict__ Pn,
    const float* __restrict__ acc,
    float* __restrict__ out, int n_nodes)
{
    const int node = blockIdx.x * 4 + (threadIdx.x >> 6);
    if (node >= n_nodes) return;
    const int lane = threadIdx.x & 63;

    const int beg = rowptr[node];
    const int end = rowptr[node + 1];

    float a0 = 0.f, a1 = 0.f, a2 = 0.f, a3 = 0.f;
    int e = beg;
    for (; e + 3 < end; e += 4) {
        const int2 p0 = epk[e + 0];
        const int2 p1 = epk[e + 1];
        const int2 p2 = epk[e + 2];
        const int2 p3 = epk[e + 3];
        const float v0 = Pn[(size_t)p0.x * OUT_FEAT + lane];
        const float v1 = Pn[(size_t)p1.x * OUT_FEAT + lane];
        const float v2 = Pn[(size_t)p2.x * OUT_FEAT + lane];
        const float v3 = Pn[(size_t)p3.x * OUT_FEAT + lane];
        a0 += __int_as_float(p0.y) * v0;
        a1 += __int_as_float(p1.y) * v1;
        a2 += __int_as_float(p2.y) * v2;
        a3 += __int_as_float(p3.y) * v3;
    }
    for (; e < end; ++e) {
        const int2 p = epk[e];
        a0 += __int_as_float(p.y) * Pn[(size_t)p.x * OUT_FEAT + lane];
    }
    const float s = acc[(size_t)node * OUT_FEAT + lane];
    out[(size_t)node * OUT_FEAT + lane] = fmaxf(s + (a0 + a1) + (a2 + a3), 0.f);
}

extern "C" void kernel_launch(void* const* d_in, const int* in_sizes, int n_in,
                              void* d_out, int out_size, void* d_ws, size_t ws_size,
                              hipStream_t stream) {
    const float* feat   = (const float*)d_in[0];
    const int*   esrc   = (const int*)  d_in[1];
    const int*   edst   = (const int*)  d_in[2];
    const float* ew     = (const float*)d_in[3];
    const float* Wself  = (const float*)d_in[4];
    const float* Wneigh = (const float*)d_in[5];

    const int n_nodes = in_sizes[0] / IN_FEAT;
    const int n_edges = in_sizes[1];

    // workspace layout (Wfrag first keeps 16B alignment for everything after)
    bf16x8* Wfrag = (bf16x8*)d_ws;                              // 4096 * 16B = 64 KB
    float* acc    = (float*)((char*)d_ws + 65536);              // N*64 f32
    float* Pn     = acc + (size_t)n_nodes * OUT_FEAT;           // N*64 f32
    int2*  epk    = (int2*)(Pn + (size_t)n_nodes * OUT_FEAT);   // E int2
    int*   cnt    = (int*)(epk + n_edges);                      // N
    int*   rowptr = cnt + n_nodes;                              // N+1
    int*   cursor = rowptr + n_nodes + 1;                       // N
    int*   bsum   = cursor + n_nodes;                           // 64
    int*   boff   = bsum + 64;                                  // 64
    float* out    = (float*)d_out;

    hipMemsetAsync(cnt, 0, (size_t)n_nodes * sizeof(int), stream);

    wfrag_build<<<16, 256, 0, stream>>>(Wself, Wneigh, Wfrag);

    const int gemm_blocks = (n_nodes + 63) / 64;
    gemm_mfma<<<gemm_blocks, 256, 0, stream>>>(feat, Wfrag, acc, Pn, n_nodes);

    hist<<<(n_edges + 255) / 256, 256, 0, stream>>>(edst, cnt, n_edges);

    const int nb = (n_nodes + 1023) / 1024;       // 49 <= 64
    scan_p1<<<nb, 1024, 0, stream>>>(cnt, bsum, n_nodes);
    scan_p2<<<1, 64, 0, stream>>>(bsum, boff, rowptr, nb, n_nodes);
    scan_p3<<<nb, 1024, 0, stream>>>(cnt, boff, rowptr, cursor, n_nodes);

    sort_edges<<<(n_edges + 255) / 256, 256, 0, stream>>>(esrc, edst, ew, cursor, epk, n_edges);

    gather<<<(n_nodes + 3) / 4, 256, 0, stream>>>(epk, rowptr, Pn, acc, out, n_nodes);
}